// Round 18
// baseline (102.522 us; speedup 1.0000x reference)
//
#include <hip/hip_runtime.h>

#define IW 512
#define IH 512
#define NPIX (IW * IH)
#define EMPTY_KEY 0xFFFFFFFFFFFFFFFFull

__global__ void init_bufs(unsigned long long* __restrict__ kb) {
    int i = blockIdx.x * blockDim.x + threadIdx.x;
    if (i < NPIX) kb[i] = EMPTY_KEY;
}

__global__ void snap_copy(const unsigned long long* __restrict__ kb,
                          unsigned long long* __restrict__ snap) {
    int i = blockIdx.x * blockDim.x + threadIdx.x;
    if (i < NPIX) snap[i] = kb[i];
}

// f32 mirror of the XLA-on-gfx950 compiled reference graph (FROZEN — passed
// absmax 0.0 in rounds 8-17):
//  - divisions lowered as a * v_rcp_f32(b)
//  - r2 contracted as fma(dx,dx, dy*dy)
//  - all other ops singly-rounded (contract(off)); matmul terms exact.
__device__ __forceinline__ bool project_voxel(
        float x, float y, float z0,
        const float* __restrict__ m1, const float* __restrict__ m2,
        float& px, float& py, float& vz) {
#pragma clang fp contract(off)
    float vh0 = ((x * m1[0]  + y * m1[4])  + z0 * m1[8])  + m1[12];
    float vh1 = ((x * m1[1]  + y * m1[5])  + z0 * m1[9])  + m1[13];
    float vh2 = ((x * m1[2]  + y * m1[6])  + z0 * m1[10]) + m1[14];
    float vh3 = ((x * m1[3]  + y * m1[7])  + z0 * m1[11]) + m1[15];

    float wv  = (fabsf(vh3) > 1e-8f) ? vh3 : 1.0f;
    float rwv = __builtin_amdgcn_rcpf(wv);
    float vx  = vh0 * rwv;
    float vy  = vh1 * rwv;
    vz        = vh2 * rwv;

    float cl0 = ((vx * m2[0] + vy * m2[4]) + vz * m2[8])  + m2[12];
    float cl1 = ((vx * m2[1] + vy * m2[5]) + vz * m2[9])  + m2[13];
    float cl3 = ((vx * m2[3] + vy * m2[7]) + vz * m2[11]) + m2[15];

    if (!(fabsf(cl3) > 1e-8f)) return false;  // valid: |w| > 1e-8 (rejects NaN)
    if (!(vz > 1e-6f)) return false;          // valid: z > 1e-6  (rejects NaN)

    float rw   = __builtin_amdgcn_rcpf(cl3);
    float ndcx = cl0 * rw;
    float ndcy = cl1 * rw;
    px = ((ndcx + 1.0f) * 0.5f) * (float)IW;
    py = ((ndcy + 1.0f) * 0.5f) * (float)IH;
    return true;
}

// One voxel's full splat chain (project -> coverage -> precheck -> atomic).
template <int SNAP>
__device__ __forceinline__ void splat_one(
        const float* __restrict__ vox, const float* __restrict__ m1,
        const float* __restrict__ m2,
        const unsigned long long* __restrict__ snap,
        unsigned long long* __restrict__ kb, int n) {
#pragma clang fp contract(off)
    // vectorized voxel read: index 6n is even -> 8B-aligned float2, + scalar
    float2 xy = *reinterpret_cast<const float2*>(vox + n * 6);
    float z0  = vox[n * 6 + 2];

    float px, py, vz;
    if (!project_voxel(xy.x, xy.y, z0, m1, m2, px, py, vz)) return;

    float fx = floorf(px);
    float fy = floorf(py);
    if (!(fx >= -1.0f && fx <= (float)IW && fy >= -1.0f && fy <= (float)IH))
        return;

    unsigned long long zhi = ((unsigned long long)__float_as_uint(vz)) << 32;
    unsigned basepid = (unsigned)n * 9u;

    for (int oy = -1; oy <= 1; ++oy) {
        for (int ox = -1; ox <= 1; ++ox) {
            float ixf = fx + (float)ox;
            float iyf = fy + (float)oy;
            if (!(ixf >= 0.0f && ixf < (float)IW &&
                  iyf >= 0.0f && iyf < (float)IH)) continue;
            float dx = (ixf + 0.5f) - px;
            float dy = (iyf + 0.5f) - py;
            float r2 = fmaf(dx, dx, dy * dy);   // frozen contraction form
            if (!(r2 <= 1.0f)) continue;
            int pix = (int)iyf * IW + (int)ixf;
            unsigned pid = basepid + (unsigned)((oy + 1) * 3 + (ox + 1));
            unsigned long long key = zhi | (unsigned long long)pid;
            if (SNAP) {
                if (key < snap[pix])            // read-only, cache-resident
                    atomicMin(&kb[pix], key);   // blind — no live-line load
            } else {
                atomicMin(&kb[pix], key);       // blind
            }
        }
    }
}

// Each thread runs TWO independent voxel chains (i and i+half) so the
// compiler can interleave their loads/projection math -> 2x memory-level
// parallelism per wave (r17 showed stages are latency-bound, not
// atomic-count-bound: VALUBusy 6%, HBM 16%, occupancy 80%).
template <int SNAP>
__global__ __launch_bounds__(256) void splat(
        const float* __restrict__ vox, const float* __restrict__ m1,
        const float* __restrict__ m2,
        const unsigned long long* __restrict__ snap,
        unsigned long long* __restrict__ kb,
        int n0, int n1) {
    int range = n1 - n0;
    int half  = (range + 1) >> 1;
    int i = blockIdx.x * blockDim.x + threadIdx.x;
    if (i >= half) return;
    int na = n0 + i;
    int nb = na + half;
    splat_one<SNAP>(vox, m1, m2, snap, kb, na);
    if (nb < n1) splat_one<SNAP>(vox, m1, m2, snap, kb, nb);
}

__global__ void resolve(const unsigned long long* __restrict__ kb,
                        const float* __restrict__ vox,
                        float* __restrict__ out) {
    int p = blockIdx.x * blockDim.x + threadIdx.x;
    if (p >= NPIX) return;
    unsigned long long key = kb[p];
    float r = 0.0f, g = 0.0f, b = 0.0f;
    if (key != EMPTY_KEY) {
        unsigned pid = (unsigned)(key & 0xFFFFFFFFull);
        unsigned n = pid / 9u;
        r = vox[n * 6 + 3];
        float2 gb = *reinterpret_cast<const float2*>(vox + n * 6 + 4); // even idx
        g = gb.x;
        b = gb.y;
    }
    __builtin_nontemporal_store(r, out + p * 3 + 0);
    __builtin_nontemporal_store(g, out + p * 3 + 1);
    __builtin_nontemporal_store(b, out + p * 3 + 2);
}

extern "C" void kernel_launch(void* const* d_in, const int* in_sizes, int n_in,
                              void* d_out, int out_size, void* d_ws, size_t ws_size,
                              hipStream_t stream) {
    const float* vox = (const float*)d_in[0];
    const float* m1  = (const float*)d_in[1];
    const float* m2  = (const float*)d_in[2];
    float* out = (float*)d_out;
    int N = in_sizes[0] / 6;

    unsigned long long* kb   = (unsigned long long*)d_ws;   // 2 MB
    unsigned long long* snap = kb + NPIX;                   // 2 MB

    const int pixblocks = (NPIX + 255) / 256;
    init_bufs<<<pixblocks, 256, 0, stream>>>(kb);

    auto stage_blocks = [](int range) {
        int half = (range + 1) >> 1;
        return (half + 255) / 256;
    };

    if (ws_size >= 2ull * NPIX * sizeof(unsigned long long)) {
        // 4-stage snapshot ladder (boundaries 1/32, 1/8, 3/8, 1) — frozen.
        int n1 = N / 32;
        int n2 = N / 8;
        int n3 = 3 * (N / 8);
        splat<0><<<stage_blocks(n1), 256, 0, stream>>>(
            vox, m1, m2, nullptr, kb, 0, n1);
        snap_copy<<<pixblocks, 256, 0, stream>>>(kb, snap);
        splat<1><<<stage_blocks(n2 - n1), 256, 0, stream>>>(
            vox, m1, m2, snap, kb, n1, n2);
        snap_copy<<<pixblocks, 256, 0, stream>>>(kb, snap);
        splat<1><<<stage_blocks(n3 - n2), 256, 0, stream>>>(
            vox, m1, m2, snap, kb, n2, n3);
        snap_copy<<<pixblocks, 256, 0, stream>>>(kb, snap);
        splat<1><<<stage_blocks(N - n3), 256, 0, stream>>>(
            vox, m1, m2, snap, kb, n3, N);
    } else {
        // minimal-ws fallback: single blind pass (round-8 style, proven)
        splat<0><<<stage_blocks(N), 256, 0, stream>>>(
            vox, m1, m2, nullptr, kb, 0, N);
    }

    resolve<<<pixblocks, 256, 0, stream>>>(kb, vox, out);
}

// Round 19
// 99.945 us; speedup vs baseline: 1.0258x; 1.0258x over previous
//
#include <hip/hip_runtime.h>

#define IW 512
#define IH 512
#define NPIX (IW * IH)
#define EMPTY_KEY 0xFFFFFFFFFFFFFFFFull

// f32 mirror of the XLA-on-gfx950 compiled reference graph (FROZEN — passed
// absmax 0.0 in rounds 8-18):
//  - divisions lowered as a * v_rcp_f32(b)
//  - r2 contracted as fma(dx,dx, dy*dy)
//  - all other ops singly-rounded (contract(off)); matmul terms exact.
__device__ __forceinline__ bool project_voxel(
        float x, float y, float z0,
        const float* __restrict__ m1, const float* __restrict__ m2,
        float& px, float& py, float& vz) {
#pragma clang fp contract(off)
    float vh0 = ((x * m1[0]  + y * m1[4])  + z0 * m1[8])  + m1[12];
    float vh1 = ((x * m1[1]  + y * m1[5])  + z0 * m1[9])  + m1[13];
    float vh2 = ((x * m1[2]  + y * m1[6])  + z0 * m1[10]) + m1[14];
    float vh3 = ((x * m1[3]  + y * m1[7])  + z0 * m1[11]) + m1[15];

    float wv  = (fabsf(vh3) > 1e-8f) ? vh3 : 1.0f;
    float rwv = __builtin_amdgcn_rcpf(wv);
    float vx  = vh0 * rwv;
    float vy  = vh1 * rwv;
    vz        = vh2 * rwv;

    float cl0 = ((vx * m2[0] + vy * m2[4]) + vz * m2[8])  + m2[12];
    float cl1 = ((vx * m2[1] + vy * m2[5]) + vz * m2[9])  + m2[13];
    float cl3 = ((vx * m2[3] + vy * m2[7]) + vz * m2[11]) + m2[15];

    if (!(fabsf(cl3) > 1e-8f)) return false;  // valid: |w| > 1e-8 (rejects NaN)
    if (!(vz > 1e-6f)) return false;          // valid: z > 1e-6  (rejects NaN)

    float rw   = __builtin_amdgcn_rcpf(cl3);
    float ndcx = cl0 * rw;
    float ndcy = cl1 * rw;
    px = ((ndcx + 1.0f) * 0.5f) * (float)IW;
    py = ((ndcy + 1.0f) * 0.5f) * (float)IH;
    return true;
}

// Lexicographic min over packed (zbits<<32 | pid) — r17's proven form
// (one voxel per thread; r18's 2-chain ILP regressed).
//  SNAP=0: blind atomicMin (converging prefix — write side only).
//  SNAP=1: pre-check against a READ-ONLY snapshot (cache-resident, never
//          invalidated), then blind atomicMin on the live kb.
// Safety: keys at a pixel only decrease; snap holds a value kb actually
// held, so key >= snap[pix] >= kb_final[pix] -> skipping cannot drop a
// winner. Min is order-invariant -> bit-exact for any stage split.
template <int SNAP>
__global__ __launch_bounds__(256) void splat(
        const float* __restrict__ vox, const float* __restrict__ m1,
        const float* __restrict__ m2,
        const unsigned long long* __restrict__ snap,
        unsigned long long* __restrict__ kb,
        int n0, int n1) {
#pragma clang fp contract(off)
    int n = n0 + blockIdx.x * blockDim.x + threadIdx.x;
    if (n >= n1) return;

    float x  = vox[n * 6 + 0];
    float y  = vox[n * 6 + 1];
    float z0 = vox[n * 6 + 2];

    float px, py, vz;
    if (!project_voxel(x, y, z0, m1, m2, px, py, vz)) return;

    float fx = floorf(px);
    float fy = floorf(py);
    if (!(fx >= -1.0f && fx <= (float)IW && fy >= -1.0f && fy <= (float)IH))
        return;

    unsigned long long zhi = ((unsigned long long)__float_as_uint(vz)) << 32;
    unsigned basepid = (unsigned)n * 9u;

    for (int oy = -1; oy <= 1; ++oy) {
        for (int ox = -1; ox <= 1; ++ox) {
            float ixf = fx + (float)ox;
            float iyf = fy + (float)oy;
            if (!(ixf >= 0.0f && ixf < (float)IW &&
                  iyf >= 0.0f && iyf < (float)IH)) continue;
            float dx = (ixf + 0.5f) - px;
            float dy = (iyf + 0.5f) - py;
            float r2 = fmaf(dx, dx, dy * dy);   // frozen contraction form
            if (!(r2 <= 1.0f)) continue;
            int pix = (int)iyf * IW + (int)ixf;
            unsigned pid = basepid + (unsigned)((oy + 1) * 3 + (ox + 1));
            unsigned long long key = zhi | (unsigned long long)pid;
            if (SNAP) {
                if (key < snap[pix])            // read-only, cache-resident
                    atomicMin(&kb[pix], key);   // blind — no live-line load
            } else {
                atomicMin(&kb[pix], key);       // blind
            }
        }
    }
}

__global__ void resolve(const unsigned long long* __restrict__ kb,
                        const float* __restrict__ vox,
                        float* __restrict__ out) {
    int p = blockIdx.x * blockDim.x + threadIdx.x;
    if (p >= NPIX) return;
    unsigned long long key = kb[p];
    float r = 0.0f, g = 0.0f, b = 0.0f;
    if (key != EMPTY_KEY) {
        unsigned pid = (unsigned)(key & 0xFFFFFFFFull);
        unsigned n = pid / 9u;
        r = vox[n * 6 + 3];
        float2 gb = *reinterpret_cast<const float2*>(vox + n * 6 + 4); // even idx
        g = gb.x;
        b = gb.y;
    }
    __builtin_nontemporal_store(r, out + p * 3 + 0);
    __builtin_nontemporal_store(g, out + p * 3 + 1);
    __builtin_nontemporal_store(b, out + p * 3 + 2);
}

extern "C" void kernel_launch(void* const* d_in, const int* in_sizes, int n_in,
                              void* d_out, int out_size, void* d_ws, size_t ws_size,
                              hipStream_t stream) {
    const float* vox = (const float*)d_in[0];
    const float* m1  = (const float*)d_in[1];
    const float* m2  = (const float*)d_in[2];
    float* out = (float*)d_out;
    int N = in_sizes[0] / 6;

    unsigned long long* kb   = (unsigned long long*)d_ws;   // 2 MB
    unsigned long long* snap = kb + NPIX;                   // 2 MB

    const size_t KB_BYTES = (size_t)NPIX * sizeof(unsigned long long);
    const int pixblocks = (NPIX + 255) / 256;

    // init via memset node: 0xFF bytes == EMPTY_KEY (graph-capturable,
    // fill-rate path instead of a wave-based kernel).
    hipMemsetAsync(kb, 0xFF, KB_BYTES, stream);

    if (ws_size >= 2 * KB_BYTES) {
        // 4-stage snapshot ladder (boundaries 1/32, 1/8, 3/8, 1) — frozen.
        // Snapshots via DMA copy nodes instead of wave-based copy kernels.
        int n1 = N / 32;
        int n2 = N / 8;
        int n3 = 3 * (N / 8);
        splat<0><<<(n1 + 255) / 256, 256, 0, stream>>>(
            vox, m1, m2, nullptr, kb, 0, n1);
        hipMemcpyAsync(snap, kb, KB_BYTES, hipMemcpyDeviceToDevice, stream);
        splat<1><<<((n2 - n1) + 255) / 256, 256, 0, stream>>>(
            vox, m1, m2, snap, kb, n1, n2);
        hipMemcpyAsync(snap, kb, KB_BYTES, hipMemcpyDeviceToDevice, stream);
        splat<1><<<((n3 - n2) + 255) / 256, 256, 0, stream>>>(
            vox, m1, m2, snap, kb, n2, n3);
        hipMemcpyAsync(snap, kb, KB_BYTES, hipMemcpyDeviceToDevice, stream);
        splat<1><<<((N - n3) + 255) / 256, 256, 0, stream>>>(
            vox, m1, m2, snap, kb, n3, N);
    } else {
        // minimal-ws fallback: single blind pass (round-8 style, proven)
        splat<0><<<(N + 255) / 256, 256, 0, stream>>>(
            vox, m1, m2, nullptr, kb, 0, N);
    }

    resolve<<<pixblocks, 256, 0, stream>>>(kb, vox, out);
}